// Round 14
// baseline (159.409 us; speedup 1.0000x reference)
//
#include <hip/hip_runtime.h>
#include <math.h>

#define LL 1024
#define DD 640
#define KK 32
#define MM 64
#define THRESH 0.2f
#define LOG2E 1.4426950408889634f

// ws layout (float units)
#define NPROJ_OFF  0                        // [1024][64] node_proj + b_edge (backbone base)
#define NPROJC_OFF (NPROJ_OFF + LL * MM)    // [1024][64] node_proj + b_edge + W0 (contact base)
#define WRT_OFF    (NPROJC_OFF + LL * MM)   // ushort[64][32]: bf16 W_edge[2+k][m], m-major
#define W1_OFF     (WRT_OFF + 1024)         // 64 f32
#define EA_OFF     (W1_OFF + MM)            // 32 f32 : -log2e/(2 sigma^2)
#define EB_OFF     (EA_OFF + KK)            // 32 f32 :  log2e*mu/sigma^2
#define EC_OFF     (EB_OFF + KK)            // 32 f32 : -log2e*mu^2/(2 sigma^2)
#define XYZ4_OFF   (EC_OFF + KK)            // [1024][4] padded coords

typedef float f32x4_t __attribute__((ext_vector_type(4)));
typedef short bf16x8_t __attribute__((ext_vector_type(8)));

union FragU { unsigned int u[4]; bf16x8_t v; };

#if __has_builtin(__builtin_amdgcn_sqrtf)
#define FSQRT __builtin_amdgcn_sqrtf
#else
#define FSQRT sqrtf
#endif

#if __has_builtin(__builtin_amdgcn_exp2f)
#define EXP2F __builtin_amdgcn_exp2f
#else
#define EXP2F(x) __expf((x) * 0.6931471805599453f)
#endif

__device__ __forceinline__ unsigned int pack_bf(float hi, float lo) {
    return __builtin_amdgcn_perm(__float_as_uint(hi), __float_as_uint(lo), 0x07060302u);
}

// Split-K node_proj GEMM (r10) + constants block; also initializes out = xyz.
__global__ __launch_bounds__(256) void prep_sk(
    const float* __restrict__ S, const float* __restrict__ xyz,
    const float* __restrict__ rbf_mu, const float* __restrict__ rbf_sigma,
    const float* __restrict__ W_edge, const float* __restrict__ b_edge,
    const float* __restrict__ W_node, float* __restrict__ ws,
    float* __restrict__ out)
{
    const int b = blockIdx.x;
    const int t = threadIdx.x;
    if (b < 256) {
        __shared__ float red[4][64][4];
        const int lane = t & 63;
        const int wave = t >> 6;
        const int r0   = (b >> 2) * 16;     // row tile
        const int n0   = (b & 3) * 16;      // col tile
        const int col  = lane & 15;
        const int quad = lane >> 4;

        f32x4_t acc = {0.f, 0.f, 0.f, 0.f};
        const float* arow = S + (size_t)(r0 + col) * DD + wave * 160 + quad * 8;
        const float* bcol = W_node + (size_t)(wave * 160 + quad * 8) * MM + n0 + col;

        #pragma unroll
        for (int ks = 0; ks < 5; ++ks) {
            const float4 a0 = *(const float4*)(arow + ks * 32);
            const float4 a1 = *(const float4*)(arow + ks * 32 + 4);
            FragU A;
            A.u[0] = pack_bf(a0.y, a0.x); A.u[1] = pack_bf(a0.w, a0.z);
            A.u[2] = pack_bf(a1.y, a1.x); A.u[3] = pack_bf(a1.w, a1.z);
            const float* bk = bcol + (size_t)ks * 32 * MM;
            const float b0 = bk[0 * MM], b1 = bk[1 * MM], b2 = bk[2 * MM], b3 = bk[3 * MM];
            const float b4 = bk[4 * MM], b5 = bk[5 * MM], b6 = bk[6 * MM], b7 = bk[7 * MM];
            FragU B;
            B.u[0] = pack_bf(b1, b0); B.u[1] = pack_bf(b3, b2);
            B.u[2] = pack_bf(b5, b4); B.u[3] = pack_bf(b7, b6);
            acc = __builtin_amdgcn_mfma_f32_16x16x32_bf16(A.v, B.v, acc, 0, 0, 0);
        }
        red[wave][lane][0] = acc[0];
        red[wave][lane][1] = acc[1];
        red[wave][lane][2] = acc[2];
        red[wave][lane][3] = acc[3];
        __syncthreads();
        const int lr  = t & 63;
        const int reg = t >> 6;
        const float v = (red[0][lr][reg] + red[1][lr][reg])
                      + (red[2][lr][reg] + red[3][lr][reg]);
        const int row = r0 + (lr >> 4) * 4 + reg;
        const int cc  = n0 + (lr & 15);
        const float vb = v + b_edge[cc];
        ws[NPROJ_OFF  + (size_t)row * MM + cc] = vb;
        ws[NPROJC_OFF + (size_t)row * MM + cc] = vb + W_edge[cc];
    } else {
        unsigned short* wrt = (unsigned short*)(ws + WRT_OFF);
        if (t < MM) ws[W1_OFF + t] = W_edge[MM + t];
        if (t < KK) {
            const float s  = rbf_sigma[t];
            const float m_ = rbf_mu[t];
            const float inv = 1.0f / (2.0f * s * s);
            ws[EA_OFF + t] = -LOG2E * inv;
            ws[EB_OFF + t] =  2.0f * LOG2E * inv * m_;
            ws[EC_OFF + t] = -LOG2E * inv * m_ * m_;
        }
        for (int idx = t; idx < KK * MM; idx += 256) {
            const int m = idx >> 5, k = idx & 31;
            unsigned int u = __float_as_uint(W_edge[(2 + k) * MM + m]);
            u = (u + 0x7fffu + ((u >> 16) & 1u)) >> 16;   // RNE to bf16
            wrt[idx] = (unsigned short)u;
        }
        for (int n = t; n < LL; n += 256) {
            float4 v;
            v.x = xyz[3 * n + 0]; v.y = xyz[3 * n + 1];
            v.z = xyz[3 * n + 2]; v.w = 0.0f;
            *(float4*)(ws + XYZ4_OFF + 4 * n) = v;
        }
        // out init: edge blocks atomically accumulate on top of xyz
        for (int idx = t; idx < 3 * LL; idx += 256) out[idx] = xyz[idx];
    }
}

// COLUMN-parallel edge kernel: block handles column j (edges i<j). The MLP
// C-init (nprojc[j] + pij*W1) is block-constant -> registers, ZERO inner-loop
// C-init loads (removes the 16 KB/iter/wave nprojc L1 stream). Per-i partials
// accumulate in LDS (waves own disjoint i residues), flushed with atomicAdds.
__global__ __launch_bounds__(256) void edge_colpar(
    const float* __restrict__ P, const float* __restrict__ w_out,
    const float* __restrict__ ws, float* __restrict__ out)
{
    __shared__ float4 lacc[LL];   // 16 KB per-i partial sums
    const int tid  = threadIdx.x;
    const int lane = tid & 63;
    const int wave = tid >> 6;
    const int quad = lane >> 4;
    const int col  = lane & 15;

    const float4* __restrict__ xyz4 = (const float4*)(ws + XYZ4_OFF);
    const unsigned short* __restrict__ wrt = (const unsigned short*)(ws + WRT_OFF);

    const int j   = (LL - 1) - (int)blockIdx.x;   // longest-first
    const int len = j - 2;                        // contacts: i in [0, j-3]

    // zero the partial table for rows we will flush
    {
        const float4 z = {0.f, 0.f, 0.f, 0.f};
        for (int n = tid; n < j; n += 256) lacc[n] = z;
    }

    // persistent register state
    FragU ar[4];
    float w1r[16], wvr[16], cjr[16];
    float aj[8], bj[8], cj[8];
    #pragma unroll
    for (int mt = 0; mt < 4; ++mt) {
        const uint4 w = *(const uint4*)(wrt + (mt * 16 + col) * KK + quad * 8);
        ar[mt].u[0] = w.x; ar[mt].u[1] = w.y; ar[mt].u[2] = w.z; ar[mt].u[3] = w.w;
        const f32x4_t w1 = *(const f32x4_t*)(ws + W1_OFF + mt * 16 + quad * 4);
        const f32x4_t wo = *(const f32x4_t*)(w_out + mt * 16 + quad * 4);
        const f32x4_t cc = *(const f32x4_t*)(ws + NPROJC_OFF + (size_t)j * MM + mt * 16 + quad * 4);
        #pragma unroll
        for (int r = 0; r < 4; ++r) {
            w1r[mt * 4 + r] = w1[r];
            wvr[mt * 4 + r] = wo[r];
            cjr[mt * 4 + r] = cc[r];
        }
    }
    #pragma unroll
    for (int jj = 0; jj < 8; ++jj) {
        aj[jj] = ws[EA_OFF + quad * 8 + jj];
        bj[jj] = ws[EB_OFF + quad * 8 + jj];
        cj[jj] = ws[EC_OFF + quad * 8 + jj];
    }

    const float4 xo = xyz4[j];
    const float xi0 = xo.x, xi1 = xo.y, xi2 = xo.z;
    const float* __restrict__ prow = P + (size_t)j * LL;   // P[j][i] == P[i][j]

    __syncthreads();   // lacc zeroed

    // ---- backbone edge (i = j-1): fp32 scalar path on wave 0 ----
    if (wave == 0 && j >= 1) {
        const int m = lane;
        const float4 xb = xyz4[j - 1];
        const float bx = xi0 - xb.x, by = xi1 - xb.y, bz = xi2 - xb.z;
        const float q2b = fmaf(bx, bx, fmaf(by, by, fmaf(bz, bz, 1e-12f)));
        const float db = FSQRT(q2b);
        float acc = ws[NPROJ_OFF + (size_t)j * MM + m] + ws[W1_OFF + m];  // etype=0, pij=1
        const uint4 wa = *(const uint4*)(wrt + m * KK);
        const uint4 wb = *(const uint4*)(wrt + m * KK + 8);
        const unsigned int wu[8] = {wa.x, wa.y, wa.z, wa.w, wb.x, wb.y, wb.z, wb.w};
        #pragma unroll
        for (int k = 0; k < KK; ++k) {
            const float r = EXP2F(fmaf(ws[EA_OFF + k], q2b,
                              fmaf(ws[EB_OFF + k], db, ws[EC_OFF + k])));
            const unsigned int h = (k & 1) ? (wu[k >> 1] & 0xffff0000u)
                                           : (wu[k >> 1] << 16);
            acc = fmaf(r, __uint_as_float(h), acc);
        }
        float gg = fmaxf(acc, 0.f) * w_out[m];
        #pragma unroll
        for (int off = 32; off > 0; off >>= 1) gg += __shfl_down(gg, off, 64);
        if (lane == 0) {
            const float gate = 1.0f / (1.0f + __expf(-gg));
            float4 v;
            v.x = gate * bx; v.y = gate * by; v.z = gate * bz; v.w = 0.f;
            lacc[j - 1] = v;   // row j-1 untouched by main loop (len = j-2)
        }
    }

    // ---- main loop: contacts i in [0, len) ----
    for (int base = wave * 64; base < len; base += 256) {
        float res[4];
        #pragma unroll
        for (int ct = 0; ct < 4; ++ct) {
            int ic = base + ct * 16 + col;
            ic = (ic < len) ? ic : (len - 1);
            const float p_n = prow[ic];             // coalesced/broadcast
            const float4 xn = xyz4[ic];
            const float dx = xi0 - xn.x, dy = xi1 - xn.y, dz = xi2 - xn.z;
            const float q2 = fmaf(dx, dx, fmaf(dy, dy, fmaf(dz, dz, 1e-12f)));
            const float dn = FSQRT(q2);

            float e[8];
            #pragma unroll
            for (int jj = 0; jj < 8; ++jj)
                e[jj] = EXP2F(fmaf(aj[jj], q2, fmaf(bj[jj], dn, cj[jj])));
            FragU bf;
            bf.u[0] = pack_bf(e[1], e[0]); bf.u[1] = pack_bf(e[3], e[2]);
            bf.u[2] = pack_bf(e[5], e[4]); bf.u[3] = pack_bf(e[7], e[6]);

            float g = 0.0f;
            #pragma unroll
            for (int mt = 0; mt < 4; ++mt) {
                f32x4_t c0;
                c0[0] = fmaf(p_n, w1r[mt*4+0], cjr[mt*4+0]);   // all registers!
                c0[1] = fmaf(p_n, w1r[mt*4+1], cjr[mt*4+1]);
                c0[2] = fmaf(p_n, w1r[mt*4+2], cjr[mt*4+2]);
                c0[3] = fmaf(p_n, w1r[mt*4+3], cjr[mt*4+3]);
                c0 = __builtin_amdgcn_mfma_f32_16x16x32_bf16(ar[mt].v, bf.v, c0, 0, 0, 0);
                g = fmaf(fmaxf(c0[0], 0.f), wvr[mt*4+0], g);
                g = fmaf(fmaxf(c0[1], 0.f), wvr[mt*4+1], g);
                g = fmaf(fmaxf(c0[2], 0.f), wvr[mt*4+2], g);
                g = fmaf(fmaxf(c0[3], 0.f), wvr[mt*4+3], g);
            }
            g += __shfl_xor(g, 16, 64);
            g += __shfl_xor(g, 32, 64);
            res[ct] = g;
        }

        // own edge i = base + lane (== base + quad*16 + col)
        const int i_own = base + lane;
        if (i_own < len) {
            float gd = res[0];
            gd = (quad == 1) ? res[1] : gd;
            gd = (quad == 2) ? res[2] : gd;
            gd = (quad == 3) ? res[3] : gd;
            const float p_own = prow[i_own];
            const float4 xn = xyz4[i_own];
            const float gate = (p_own > THRESH) ? (1.0f / (1.0f + __expf(-gd))) : 0.0f;
            float4 v = lacc[i_own];                 // waves own disjoint residues
            v.x = fmaf(gate, xi0 - xn.x, v.x);
            v.y = fmaf(gate, xi1 - xn.y, v.y);
            v.z = fmaf(gate, xi2 - xn.z, v.z);
            lacc[i_own] = v;
        }
    }

    __syncthreads();
    // flush: out[i] += lacc[i] (out pre-initialized with xyz by prep)
    for (int n = tid; n < j; n += 256) {
        const float4 v = lacc[n];
        atomicAdd(out + n * 3 + 0, v.x);
        atomicAdd(out + n * 3 + 1, v.y);
        atomicAdd(out + n * 3 + 2, v.z);
    }
}

extern "C" void kernel_launch(void* const* d_in, const int* in_sizes, int n_in,
                              void* d_out, int out_size, void* d_ws, size_t ws_size,
                              hipStream_t stream) {
    const float* S         = (const float*)d_in[0];
    const float* P         = (const float*)d_in[1];
    const float* xyz       = (const float*)d_in[2];
    const float* rbf_mu    = (const float*)d_in[3];
    const float* rbf_sigma = (const float*)d_in[4];
    const float* W_edge    = (const float*)d_in[5];
    const float* b_edge    = (const float*)d_in[6];
    const float* W_node    = (const float*)d_in[7];
    const float* w_out     = (const float*)d_in[8];
    float* out = (float*)d_out;
    float* ws  = (float*)d_ws;

    prep_sk<<<257, 256, 0, stream>>>(S, xyz, rbf_mu, rbf_sigma,
                                     W_edge, b_edge, W_node, ws, out);
    edge_colpar<<<LL, 256, 0, stream>>>(P, w_out, ws, out);
}